// Round 7
// baseline (40.079 us; speedup 1.0000x reference)
//
#include <hip/hip_runtime.h>
#include <hip/hip_bf16.h>

// Fused 3-layer GCN + mean-pool + mask, FP8(e4m3) datapath, 2-kernel pipeline:
//   K0 prep_w:  W1,W2 -> fragment-ordered fp8 in ws[0,32K)
//   K1 xw1:     XW1^T per graph (fp8, swizzled, 16KB/graph) -> ws[32K, 32K+8MB)
//   K2 gcn_main<1>: per-graph A-build + A@XW1 + BN1 + H1@W2 + A@H2 + BN2 +
//               weighted colsum + W3 matvec + mask.
// Round-7 change: gcn_main 512->256 threads (4 waves), 1 graph/WG, 4 WG/CU
// (was 2) -> 4 interleaved phase-chains per CU. Each wave: 1 m-tile x 4
// n-tiles, 4 f32x16 accumulators.
//
// K2 LDS: An[0,16K) fp8 swizzled (u4 edge counts overlay [0,8K)),
//         Xb[16K,32K) fp8 layer buffer, misc @32K.  Total 37892 B -> 4 WG/CU.

#define NGRAPH 512
#define EPG 1024
#define NEDGE (NGRAPH * EPG)
#define NEGV -10000000000.0f
#define LDS_MAIN 37892
#define WS_NEED (32768 + (size_t)NGRAPH * 16384)

typedef float f32x16 __attribute__((ext_vector_type(16)));
typedef float f32x4  __attribute__((ext_vector_type(4)));

#define MFMA8(a, b, c) __builtin_amdgcn_mfma_f32_32x32x16_fp8_fp8(a, b, c, 0, 0, 0)

// 128B rows; XOR row into the 8B-slot bits -> 2-way max on b64 reads
__device__ __forceinline__ unsigned swz8(unsigned row, unsigned byte_in_row) {
  return ((row << 7) + byte_in_row) ^ ((row & 15u) << 3);
}

__device__ __forceinline__ unsigned pk4(float a, float b, float c, float d) {
  int r = __builtin_amdgcn_cvt_pk_fp8_f32(a, b, 0, false);
  r = __builtin_amdgcn_cvt_pk_fp8_f32(c, d, r, true);
  return (unsigned)r;
}

// W [fi][fo] f32 -> fragment-ordered fp8 W^T, 8B per (layer,nt,ks,lane)
__global__ void prep_w(const float* __restrict__ W1, const float* __restrict__ W2,
                       unsigned char* __restrict__ wf) {
  int gid = blockIdx.x * 64 + threadIdx.x;      // 0..4095, 8 fp8 each
  int l = gid >> 11, r = gid & 2047;
  int lane = r & 63, ks = (r >> 6) & 7, nt = r >> 9;
  const float* W = l ? W2 : W1;
  int fo = nt * 32 + (lane & 31);
  int k0 = ks * 16 + (lane >> 5) * 8;
  uint2 o;
  o.x = pk4(W[(k0 + 0) * 128 + fo], W[(k0 + 1) * 128 + fo],
            W[(k0 + 2) * 128 + fo], W[(k0 + 3) * 128 + fo]);
  o.y = pk4(W[(k0 + 4) * 128 + fo], W[(k0 + 5) * 128 + fo],
            W[(k0 + 6) * 128 + fo], W[(k0 + 7) * 128 + fo]);
  ((uint2*)wf)[gid] = o;
}

// K1: XW1t[g][fo][node] fp8 swizzled -> ws (one WG per graph, streaming)
__global__ __launch_bounds__(512, 4) void xw1_kernel(
    const float* __restrict__ x, const unsigned char* __restrict__ wf,
    unsigned char* __restrict__ xw1t) {
  extern __shared__ char sm[];
  char* XbL = sm;            // 16K: x fp8 [node][fi] swizzled
  char* OtL = sm + 16384;    // 16K: out staging [fo][node] swizzled

  const int tid = threadIdx.x;
  const int g   = blockIdx.x;
  const int lane = tid & 63;
  const int l31  = lane & 31;
  const int hi   = lane >> 5;
  const int wid  = tid >> 6;
  const int mt   = wid >> 1;
  const int nt0  = (wid & 1) * 2;

  const f32x4* xg = (const f32x4*)(x + (size_t)g * 128 * 128);
  f32x4 xr[8];
#pragma unroll
  for (int j = 0; j < 8; ++j) xr[j] = xg[tid + 512 * j];
#pragma unroll
  for (int j = 0; j < 8; ++j) {
    int k = tid + 512 * j;
    *(unsigned*)(XbL + swz8(k >> 5, (k & 31) * 4)) =
        pk4(xr[j][0], xr[j][1], xr[j][2], xr[j][3]);
  }
  __syncthreads();

  f32x16 c0 = {}, c1 = {};
#pragma unroll
  for (int ks = 0; ks < 8; ++ks) {
    long wA = *(const long*)(wf + (nt0 + 0) * 4096 + ks * 512 + lane * 8);
    long wB = *(const long*)(wf + (nt0 + 1) * 4096 + ks * 512 + lane * 8);
    long a  = *(const long*)(XbL + swz8(mt * 32 + l31, ks * 16 + hi * 8));
    c0 = MFMA8(a, wA, c0);
    c1 = MFMA8(a, wB, c1);
  }
#pragma unroll
  for (int n = 0; n < 2; ++n) {
    int f = (nt0 + n) * 32 + l31;
    const f32x16& c = n ? c1 : c0;
#pragma unroll
    for (int q = 0; q < 4; ++q) {
      int n0 = mt * 32 + q * 8 + hi * 4;
      *(unsigned*)(OtL + swz8(f, n0)) =
          pk4(c[q * 4 + 0], c[q * 4 + 1], c[q * 4 + 2], c[q * 4 + 3]);
    }
  }
  __syncthreads();

  uint4* dst = (uint4*)(xw1t + (size_t)g * 16384);
#pragma unroll
  for (int it = 0; it < 2; ++it) {
    int idx = tid + 512 * it;
    dst[idx] = ((const uint4*)OtL)[idx];
  }
}

template <int SPLIT>
__global__ __launch_bounds__(256, 4) void gcn_main(
    const float* __restrict__ x, const int* __restrict__ ei,
    const unsigned char* __restrict__ wf, const unsigned char* __restrict__ xw1t,
    const float* __restrict__ b1v, const float* __restrict__ g1v,
    const float* __restrict__ be1v, const float* __restrict__ rm1v,
    const float* __restrict__ rv1v,
    const float* __restrict__ b2v, const float* __restrict__ g2v,
    const float* __restrict__ be2v, const float* __restrict__ rm2v,
    const float* __restrict__ rv2v,
    const float* __restrict__ W3g, const float* __restrict__ b3v,
    float* __restrict__ out) {
  extern __shared__ char sm[];
  char* AnB = sm;                                // fp8[128][128] swizzled
  char* XbB = sm + 16384;                        // fp8[128][128] swizzled
  unsigned* cntW = (unsigned*)sm;                // overlay: u4 counts [2048]
  unsigned* deg  = (unsigned*)(sm + 32768);
  float*    dis  = (float*)(sm + 33280);
  unsigned* conn = (unsigned*)(sm + 33792);
  float*    csum = (float*)(sm + 34304);
  float*    scl1 = (float*)(sm + 34816);
  float*    shf1 = (float*)(sm + 35328);
  float*    scl2 = (float*)(sm + 35840);
  float*    shf2 = (float*)(sm + 36352);
  float*    vred = (float*)(sm + 36864);
  float*    vout = (float*)(sm + 37376);
  int*     minid = (int*)(sm + 37888);

  const int tid = threadIdx.x;                   // 0..255, 4 waves
  const int g   = blockIdx.x;
  const int lane = tid & 63;
  const int wid  = tid >> 6;                     // 0..3 = m-tile
  const int l31  = lane & 31;
  const int hi   = lane >> 5;
  const int mt   = wid;

  // ---- early global loads ----
  int es[4], ed[4];
#pragma unroll
  for (int j = 0; j < 4; ++j) {
    int e = g * EPG + tid + 256 * j;
    es[j] = ei[e] & 127;
    ed[j] = ei[NEDGE + e] & 127;
  }
  uint4 xcp[4];
  if (SPLIT) {
    const uint4* src = (const uint4*)(xw1t + (size_t)g * 16384);
#pragma unroll
    for (int it = 0; it < 4; ++it) xcp[it] = src[tid + 256 * it];
  }

  // ---- P0: zero cnt, init misc, fill Xb ----
  uint4 z4; z4.x = 0; z4.y = 0; z4.z = 0; z4.w = 0;
#pragma unroll
  for (int it = 0; it < 2; ++it) ((uint4*)cntW)[tid + 256 * it] = z4;
  if (tid < 128) { deg[tid] = 1u; conn[tid] = 0u; vred[tid] = 0.f; vout[tid] = 0.f; }
  if (tid == 0) *minid = 128;
  if (SPLIT) {
#pragma unroll
    for (int it = 0; it < 4; ++it) ((uint4*)XbB)[tid + 256 * it] = xcp[it];
  } else {
    const f32x4* xg = (const f32x4*)(x + (size_t)g * 128 * 128);
#pragma unroll
    for (int j = 0; j < 16; ++j) {
      int k = tid + 256 * j;
      f32x4 v = xg[k];
      *(unsigned*)(XbB + swz8(k >> 5, (k & 31) * 4)) =
          pk4(v[0], v[1], v[2], v[3]);
    }
  }
  __syncthreads();

  // ---- P1: edge atomics (+ GEMM1-L1a if fused) ----
#pragma unroll
  for (int j = 0; j < 4; ++j) {
    atomicAdd(&cntW[ed[j] * 16 + (es[j] >> 3)], 1u << (4 * (es[j] & 7)));
    atomicAdd(&deg[ed[j]], 1u);
    conn[es[j]] = 1u;
    conn[ed[j]] = 1u;
  }
  f32x16 c0 = {}, c1 = {}, c2 = {}, c3 = {};
  if (!SPLIT) {
#pragma unroll
    for (int ks = 0; ks < 4; ++ks) {
      long a  = *(const long*)(XbB + swz8(mt * 32 + l31, ks * 16 + hi * 8));
      long w0 = *(const long*)(wf + 0 * 4096 + ks * 512 + lane * 8);
      long w1 = *(const long*)(wf + 1 * 4096 + ks * 512 + lane * 8);
      long w2 = *(const long*)(wf + 2 * 4096 + ks * 512 + lane * 8);
      long w3 = *(const long*)(wf + 3 * 4096 + ks * 512 + lane * 8);
      c0 = MFMA8(a, w0, c0); c1 = MFMA8(a, w1, c1);
      c2 = MFMA8(a, w2, c2); c3 = MFMA8(a, w3, c3);
    }
  }
  __syncthreads();

  // ---- P2: (GEMM1-L1b) + cnt->regs + dis/csum/BN params/minid ----
  if (!SPLIT) {
#pragma unroll
    for (int ks = 4; ks < 8; ++ks) {
      long a  = *(const long*)(XbB + swz8(mt * 32 + l31, ks * 16 + hi * 8));
      long w0 = *(const long*)(wf + 0 * 4096 + ks * 512 + lane * 8);
      long w1 = *(const long*)(wf + 1 * 4096 + ks * 512 + lane * 8);
      long w2 = *(const long*)(wf + 2 * 4096 + ks * 512 + lane * 8);
      long w3 = *(const long*)(wf + 3 * 4096 + ks * 512 + lane * 8);
      c0 = MFMA8(a, w0, c0); c1 = MFMA8(a, w1, c1);
      c2 = MFMA8(a, w2, c2); c3 = MFMA8(a, w3, c3);
    }
  }
  uint4 cw0 = ((const uint4*)cntW)[tid * 2 + 0];   // words d*16+qh*8 .. +3
  uint4 cw1 = ((const uint4*)cntW)[tid * 2 + 1];   // words d*16+qh*8+4 .. +7
  if (tid < 128) {
    float dv = rsqrtf((float)deg[tid]);
    dis[tid] = dv;
    csum[tid] = dv * dv;
    float s1 = rsqrtf(rv1v[tid] + 1e-5f) * g1v[tid];
    scl1[tid] = s1;
    shf1[tid] = be1v[tid] + (b1v[tid] - rm1v[tid]) * s1;
    float s2 = rsqrtf(rv2v[tid] + 1e-5f) * g2v[tid];
    scl2[tid] = s2;
    shf2[tid] = be2v[tid] + (b2v[tid] - rm2v[tid]) * s2;
    if (conn[tid]) atomicMin(minid, tid);
  }
  __syncthreads();

  // ---- P3: An fp8 write (overwrites cnt) + csum atomics (+ Ht write) ----
  {
    int d = tid >> 1, qh = tid & 1;              // row d, col half qh (64 cols)
#pragma unroll
    for (int qq = 0; qq < 2; ++qq) {
      int q = qh * 2 + qq;                       // 32-col group
      unsigned cwv[4];
      if (qq == 0) { cwv[0] = cw0.x; cwv[1] = cw0.y; cwv[2] = cw0.z; cwv[3] = cw0.w; }
      else         { cwv[0] = cw1.x; cwv[1] = cw1.y; cwv[2] = cw1.z; cwv[3] = cw1.w; }
      float dd = dis[d];
#pragma unroll
      for (int j = 0; j < 4; ++j) {
        f32x4 dsa = *(const f32x4*)(dis + q * 32 + j * 8);
        f32x4 dsb = *(const f32x4*)(dis + q * 32 + j * 8 + 4);
        float v[8];
#pragma unroll
        for (int i = 0; i < 8; ++i) {
          int s = q * 32 + j * 8 + i;
          float cf = (float)((cwv[j] >> (4 * i)) & 15u);
          float val = cf * dd * (i < 4 ? dsa[i] : dsb[i - 4]);
          if (s == d) val += dd * dd;
          v[i] = val;
        }
        uint2 o;
        o.x = pk4(v[0], v[1], v[2], v[3]);
        o.y = pk4(v[4], v[5], v[6], v[7]);
        *(uint2*)(AnB + swz8(d, q * 32 + j * 8)) = o;
      }
    }
  }
#pragma unroll
  for (int j = 0; j < 4; ++j)
    atomicAdd(&csum[es[j]], dis[es[j]] * dis[ed[j]]);
  if (!SPLIT) {
#pragma unroll
    for (int n = 0; n < 4; ++n) {
      int f = n * 32 + l31;
      const f32x16& c = (n == 0) ? c0 : (n == 1) ? c1 : (n == 2) ? c2 : c3;
#pragma unroll
      for (int q = 0; q < 4; ++q) {
        int n0 = mt * 32 + q * 8 + hi * 4;
        *(unsigned*)(XbB + swz8(f, n0)) =
            pk4(c[q * 4 + 0], c[q * 4 + 1], c[q * 4 + 2], c[q * 4 + 3]);
      }
    }
  }
  __syncthreads();

  // ---- P4: GEMM2-L1 ((A H1)^T = Ht . An), 4 n-tiles/wave ----
  f32x16 d0 = {}, d1 = {}, d2 = {}, d3 = {};
#pragma unroll
  for (int ks = 0; ks < 8; ++ks) {
    long am = *(const long*)(XbB + swz8(mt * 32 + l31, ks * 16 + hi * 8));
    long b0 = *(const long*)(AnB + swz8(0 * 32 + l31, ks * 16 + hi * 8));
    long b1 = *(const long*)(AnB + swz8(1 * 32 + l31, ks * 16 + hi * 8));
    long b2 = *(const long*)(AnB + swz8(2 * 32 + l31, ks * 16 + hi * 8));
    long b3 = *(const long*)(AnB + swz8(3 * 32 + l31, ks * 16 + hi * 8));
    d0 = MFMA8(am, b0, d0); d1 = MFMA8(am, b1, d1);
    d2 = MFMA8(am, b2, d2); d3 = MFMA8(am, b3, d3);
  }
  __syncthreads();

  // ---- P5: BN1+ReLU -> Xb[node][feat] ----
#pragma unroll
  for (int n = 0; n < 4; ++n) {
    int dn = n * 32 + l31;                       // destination node
    const f32x16& dd = (n == 0) ? d0 : (n == 1) ? d1 : (n == 2) ? d2 : d3;
#pragma unroll
    for (int q = 0; q < 4; ++q) {
      int f0 = mt * 32 + q * 8 + hi * 4;
      f32x4 s4 = *(const f32x4*)(scl1 + f0);
      f32x4 h4 = *(const f32x4*)(shf1 + f0);
      *(unsigned*)(XbB + swz8(dn, f0)) =
          pk4(fmaxf(dd[q * 4 + 0] * s4[0] + h4[0], 0.f),
              fmaxf(dd[q * 4 + 1] * s4[1] + h4[1], 0.f),
              fmaxf(dd[q * 4 + 2] * s4[2] + h4[2], 0.f),
              fmaxf(dd[q * 4 + 3] * s4[3] + h4[3], 0.f));
    }
  }
  __syncthreads();

  // ---- P6: GEMM1-L2 (H1 @ W2, W2 frags from L2) ----
  c0 = f32x16{}; c1 = f32x16{}; c2 = f32x16{}; c3 = f32x16{};
#pragma unroll
  for (int ks = 0; ks < 8; ++ks) {
    long a  = *(const long*)(XbB + swz8(mt * 32 + l31, ks * 16 + hi * 8));
    long w0 = *(const long*)(wf + 16384 + 0 * 4096 + ks * 512 + lane * 8);
    long w1 = *(const long*)(wf + 16384 + 1 * 4096 + ks * 512 + lane * 8);
    long w2 = *(const long*)(wf + 16384 + 2 * 4096 + ks * 512 + lane * 8);
    long w3 = *(const long*)(wf + 16384 + 3 * 4096 + ks * 512 + lane * 8);
    c0 = MFMA8(a, w0, c0); c1 = MFMA8(a, w1, c1);
    c2 = MFMA8(a, w2, c2); c3 = MFMA8(a, w3, c3);
  }
  __syncthreads();

  // ---- P7: Ht2 write ----
#pragma unroll
  for (int n = 0; n < 4; ++n) {
    int f = n * 32 + l31;
    const f32x16& c = (n == 0) ? c0 : (n == 1) ? c1 : (n == 2) ? c2 : c3;
#pragma unroll
    for (int q = 0; q < 4; ++q) {
      int n0 = mt * 32 + q * 8 + hi * 4;
      *(unsigned*)(XbB + swz8(f, n0)) =
          pk4(c[q * 4 + 0], c[q * 4 + 1], c[q * 4 + 2], c[q * 4 + 3]);
    }
  }
  __syncthreads();

  // ---- P8: GEMM2-L2 + BN2+ReLU+csum-scale + shfl-reduce -> vred ----
  d0 = f32x16{}; d1 = f32x16{}; d2 = f32x16{}; d3 = f32x16{};
#pragma unroll
  for (int ks = 0; ks < 8; ++ks) {
    long am = *(const long*)(XbB + swz8(mt * 32 + l31, ks * 16 + hi * 8));
    long b0 = *(const long*)(AnB + swz8(0 * 32 + l31, ks * 16 + hi * 8));
    long b1 = *(const long*)(AnB + swz8(1 * 32 + l31, ks * 16 + hi * 8));
    long b2 = *(const long*)(AnB + swz8(2 * 32 + l31, ks * 16 + hi * 8));
    long b3 = *(const long*)(AnB + swz8(3 * 32 + l31, ks * 16 + hi * 8));
    d0 = MFMA8(am, b0, d0); d1 = MFMA8(am, b1, d1);
    d2 = MFMA8(am, b2, d2); d3 = MFMA8(am, b3, d3);
  }
  {
    float cs0 = csum[0 * 32 + l31];
    float cs1 = csum[1 * 32 + l31];
    float cs2 = csum[2 * 32 + l31];
    float cs3 = csum[3 * 32 + l31];
#pragma unroll
    for (int q = 0; q < 4; ++q) {
      int f0 = mt * 32 + q * 8 + hi * 4;
      f32x4 s4 = *(const f32x4*)(scl2 + f0);
      f32x4 h4 = *(const f32x4*)(shf2 + f0);
#pragma unroll
      for (int j = 0; j < 4; ++j) {
        float s = fmaxf(d0[q * 4 + j] * s4[j] + h4[j], 0.f) * cs0 +
                  fmaxf(d1[q * 4 + j] * s4[j] + h4[j], 0.f) * cs1 +
                  fmaxf(d2[q * 4 + j] * s4[j] + h4[j], 0.f) * cs2 +
                  fmaxf(d3[q * 4 + j] * s4[j] + h4[j], 0.f) * cs3;
        s += __shfl_xor(s, 1, 32);
        s += __shfl_xor(s, 2, 32);
        s += __shfl_xor(s, 4, 32);
        s += __shfl_xor(s, 8, 32);
        s += __shfl_xor(s, 16, 32);
        if (l31 == 0) atomicAdd(&vred[f0 + j], s);
      }
    }
  }
  __syncthreads();

  // ---- P9: vout[fo] = sum_fi vred[fi] * W3[fi][fo] (W3 from L2) ----
  {
    int fo = tid & 127, fq = tid >> 7;           // fq 0..1, 64 fi each
    float acc0 = 0.f, acc1 = 0.f;
#pragma unroll
    for (int i = 0; i < 64; i += 2) {
      int fi = fq * 64 + i;
      acc0 += vred[fi] * W3g[fi * 128 + fo];
      acc1 += vred[fi + 1] * W3g[(fi + 1) * 128 + fo];
    }
    atomicAdd(&vout[fo], acc0 + acc1);
  }
  __syncthreads();

  // ---- P10: mask + output ----
  if (tid < 128) {
    bool msk = (conn[tid] != 0u) && (tid != *minid);
    float val = vout[tid] * (1.0f / 128.0f) + b3v[tid];
    out[(size_t)g * 128 + tid] = msk ? NEGV : val;
  }
}

extern "C" void kernel_launch(void* const* d_in, const int* in_sizes, int n_in,
                              void* d_out, int out_size, void* d_ws, size_t ws_size,
                              hipStream_t stream) {
  const float* x   = (const float*)d_in[0];
  const int*   ei  = (const int*)d_in[1];
  // d_in[2] = batch (unused; graphs are contiguous 128-node blocks)
  const float* W1  = (const float*)d_in[3];
  const float* b1  = (const float*)d_in[4];
  const float* g1  = (const float*)d_in[5];
  const float* be1 = (const float*)d_in[6];
  const float* rm1 = (const float*)d_in[7];
  const float* rv1 = (const float*)d_in[8];
  const float* W2  = (const float*)d_in[9];
  const float* b2  = (const float*)d_in[10];
  const float* g2  = (const float*)d_in[11];
  const float* be2 = (const float*)d_in[12];
  const float* rm2 = (const float*)d_in[13];
  const float* rv2 = (const float*)d_in[14];
  const float* W3  = (const float*)d_in[15];
  const float* b3  = (const float*)d_in[16];
  unsigned char* wf   = (unsigned char*)d_ws;          // 32 KB fp8 W frags
  unsigned char* xw1t = (unsigned char*)d_ws + 32768;  // 8 MB XW1^T fp8

  prep_w<<<dim3(64), dim3(64), 0, stream>>>(W1, W2, wf);
  if (ws_size >= WS_NEED) {
    xw1_kernel<<<dim3(NGRAPH), dim3(512), 32768, stream>>>(x, wf, xw1t);
    gcn_main<1><<<dim3(NGRAPH), dim3(256), LDS_MAIN, stream>>>(
        x, ei, wf, xw1t, b1, g1, be1, rm1, rv1, b2, g2, be2, rm2, rv2, W3, b3,
        (float*)d_out);
  } else {
    gcn_main<0><<<dim3(NGRAPH), dim3(256), LDS_MAIN, stream>>>(
        x, ei, wf, xw1t, b1, g1, be1, rm1, rv1, b2, g2, be2, rm2, rv2, W3, b3,
        (float*)d_out);
  }
}